// Round 1
// baseline (96.103 us; speedup 1.0000x reference)
//
#include <hip/hip_runtime.h>
#include <math.h>

#define BATCH 8192
#define DIM   128
#define E1    256
#define E2    128
#define DC1   64
#define DC2   32

// output float offsets (x_hat, adj, mu, lv concatenated)
#define OUT_XHAT 0
#define OUT_ADJ  (BATCH*DIM)                 // 1048576
#define OUT_MU   (OUT_ADJ + DIM*DIM)         // 1064960
#define OUT_LV   (OUT_MU + BATCH*DIM)        // 2113536

// workspace float offsets
#define WS_AHAT 0
#define WS_V    (DIM*DIM)                    // 16384
#define WS_Z    (WS_V + 64)                  // 16448 (16B aligned)

// ---------------------------------------------------------------------------
// Kernel A: adjacency (exact, library expf), normalized a_hat, v = Wf @ Wg1
// ---------------------------------------------------------------------------
__global__ __launch_bounds__(128) void graph_kernel(
    const float* __restrict__ logits, const float* __restrict__ Wf,
    const float* __restrict__ Wg1, const int* __restrict__ itp,
    float* __restrict__ out, float* __restrict__ ws)
{
    __shared__ float g_s[DIM * DIM];     // 64 KB
    __shared__ float rdout_s[DIM];
    const int j = threadIdx.x;           // column
    const int it = itp[0];

    float din = 0.0f;
    for (int i = 0; i < DIM; ++i) {
        float l = logits[i * DIM + j];
        float gv = 1.0f / (1.0f + expf(-l));   // precise expf: threshold boundary safety
        if (i == j) gv = 1.0f;
        if (it > 50 && gv < 0.1f) gv = 0.0f;
        g_s[i * DIM + j] = gv;
        if (gv > 0.0f) din += 1.0f;
    }
    const float rin = 1.0f / sqrtf(fmaxf(din, 1.0f));
    __syncthreads();
    {
        const int i = threadIdx.x;       // row
        float dout = 0.0f;
        for (int jj = 0; jj < DIM; ++jj)
            if (g_s[i * DIM + jj] > 0.0f) dout += 1.0f;
        rdout_s[i] = 1.0f / sqrtf(fmaxf(dout, 1.0f));
    }
    __syncthreads();
    for (int i = 0; i < DIM; ++i) {
        float gv = g_s[i * DIM + j];
        out[OUT_ADJ + i * DIM + j] = gv;
        ws[WS_AHAT + i * DIM + j] = gv * rdout_s[i] * rin;
    }
    // v = W_feat (1x64) @ W_g1 (64x32)
    if (j < DC2) {
        float acc = 0.0f;
        for (int k = 0; k < DC1; ++k) acc += Wf[k] * Wg1[k * DC2 + j];
        ws[WS_V + j] = acc;
    }
}

// ---------------------------------------------------------------------------
// Kernel B: fused VAE encoder. 16 batch rows per block, 256 threads.
// h1 = relu(x@W1+b1); h2 = relu(h1@W2+b2); mu/lv; z = mu + eps*exp(0.5*lv)
// ---------------------------------------------------------------------------
#define BR 16
__global__ __launch_bounds__(256) void encoder_kernel(
    const float* __restrict__ x,   const float* __restrict__ eps,
    const float* __restrict__ W1,  const float* __restrict__ b1,
    const float* __restrict__ W2,  const float* __restrict__ b2,
    const float* __restrict__ Wmu, const float* __restrict__ bmu,
    const float* __restrict__ Wlv, const float* __restrict__ blv,
    float* __restrict__ out, float* __restrict__ ws)
{
    __shared__ float xs [BR][DIM];   //  8 KB
    __shared__ float h1s[BR][E1];    // 16 KB
    __shared__ float h2s[BR][E2];    //  8 KB

    const int t = threadIdx.x;
    const int row0 = blockIdx.x * BR;

    // stage x tile (2048 floats) coalesced float4
    {
        const float4* xg = reinterpret_cast<const float4*>(x + (size_t)row0 * DIM);
        float4* xl = reinterpret_cast<float4*>(&xs[0][0]);
        #pragma unroll
        for (int p = 0; p < 2; ++p) xl[t + 256 * p] = xg[t + 256 * p];
    }
    __syncthreads();

    // ---- layer 1: 16 x 256, thread = 4 rows x 4 cols ----
    {
        const int tc = t & 63, tr = t >> 6;          // wave-uniform tr -> LDS broadcast
        float acc[4][4] = {};
        for (int k = 0; k < DIM; ++k) {
            float w[4];
            #pragma unroll
            for (int jc = 0; jc < 4; ++jc) w[jc] = W1[k * E1 + tc + 64 * jc];
            #pragma unroll
            for (int ir = 0; ir < 4; ++ir) {
                float a = xs[tr * 4 + ir][k];
                #pragma unroll
                for (int jc = 0; jc < 4; ++jc) acc[ir][jc] = fmaf(a, w[jc], acc[ir][jc]);
            }
        }
        #pragma unroll
        for (int jc = 0; jc < 4; ++jc) {
            float bb = b1[tc + 64 * jc];
            #pragma unroll
            for (int ir = 0; ir < 4; ++ir)
                h1s[tr * 4 + ir][tc + 64 * jc] = fmaxf(acc[ir][jc] + bb, 0.0f);
        }
    }
    __syncthreads();

    // ---- layer 2: 16 x 128, thread = 2 rows x 4 cols ----
    {
        const int tc = t & 31, tr = t >> 5;
        float acc[2][4] = {};
        for (int k = 0; k < E1; ++k) {
            float w[4];
            #pragma unroll
            for (int jc = 0; jc < 4; ++jc) w[jc] = W2[k * E2 + tc + 32 * jc];
            #pragma unroll
            for (int ir = 0; ir < 2; ++ir) {
                float a = h1s[tr * 2 + ir][k];
                #pragma unroll
                for (int jc = 0; jc < 4; ++jc) acc[ir][jc] = fmaf(a, w[jc], acc[ir][jc]);
            }
        }
        #pragma unroll
        for (int jc = 0; jc < 4; ++jc) {
            float bb = b2[tc + 32 * jc];
            #pragma unroll
            for (int ir = 0; ir < 2; ++ir)
                h2s[tr * 2 + ir][tc + 32 * jc] = fmaxf(acc[ir][jc] + bb, 0.0f);
        }
    }
    __syncthreads();

    // ---- mu, lv (fused), z ----
    {
        const int tc = t & 31, tr = t >> 5;
        float amu[2][4] = {}, alv[2][4] = {};
        for (int k = 0; k < E2; ++k) {
            float wm[4], wl[4];
            #pragma unroll
            for (int jc = 0; jc < 4; ++jc) {
                wm[jc] = Wmu[k * DIM + tc + 32 * jc];
                wl[jc] = Wlv[k * DIM + tc + 32 * jc];
            }
            #pragma unroll
            for (int ir = 0; ir < 2; ++ir) {
                float a = h2s[tr * 2 + ir][k];
                #pragma unroll
                for (int jc = 0; jc < 4; ++jc) {
                    amu[ir][jc] = fmaf(a, wm[jc], amu[ir][jc]);
                    alv[ir][jc] = fmaf(a, wl[jc], alv[ir][jc]);
                }
            }
        }
        #pragma unroll
        for (int jc = 0; jc < 4; ++jc) {
            const int c = tc + 32 * jc;
            const float bm = bmu[c], bl = blv[c];
            #pragma unroll
            for (int ir = 0; ir < 2; ++ir) {
                const int r = tr * 2 + ir;
                const int gidx = (row0 + r) * DIM + c;
                float mu = amu[ir][jc] + bm;
                float lv = alv[ir][jc] + bl;
                out[OUT_MU + gidx] = mu;
                out[OUT_LV + gidx] = lv;
                ws[WS_Z + gidx] = fmaf(eps[gidx], __expf(0.5f * lv), mu);
            }
        }
    }
}

// ---------------------------------------------------------------------------
// Kernel C: fused GCN decoder.  s = z@ahat ; t = sum_c tanh(s*v+b)*w2 ; xhat = t@ahat + bg2
// 16 rows per block, 256 threads. ahat staged in LDS; z/t share one buffer.
// ---------------------------------------------------------------------------
#define BRC 16
__global__ __launch_bounds__(256) void decoder_kernel(
    const float* __restrict__ bg1, const float* __restrict__ Wg2,
    const float* __restrict__ bg2,
    float* __restrict__ out, const float* __restrict__ ws)
{
    __shared__ float as_[DIM * DIM];     // 64 KB
    __shared__ float zts[BRC][DIM];      //  8 KB : z in phase 2, t in phase 3/4
    __shared__ float vc[DC2], bgs[DC2], w2s[DC2];

    const int t = threadIdx.x;
    const int row0 = blockIdx.x * BRC;

    // stage a_hat + z tile
    {
        const float4* ag = reinterpret_cast<const float4*>(ws + WS_AHAT);
        float4* al = reinterpret_cast<float4*>(as_);
        #pragma unroll
        for (int p = 0; p < 16; ++p) al[t + 256 * p] = ag[t + 256 * p];
        const float4* zg = reinterpret_cast<const float4*>(ws + WS_Z + (size_t)row0 * DIM);
        float4* zl = reinterpret_cast<float4*>(&zts[0][0]);
        #pragma unroll
        for (int p = 0; p < 2; ++p) zl[t + 256 * p] = zg[t + 256 * p];
    }
    if (t < DC2) { vc[t] = ws[WS_V + t]; bgs[t] = bg1[t]; w2s[t] = Wg2[t]; }
    __syncthreads();

    const int tc = t & 31, tr = t >> 5;

    // ---- phase 2: s = z @ ahat (2 rows x 4 cols per thread) ----
    float s[2][4] = {};
    for (int k = 0; k < DIM; ++k) {
        float a[4];
        #pragma unroll
        for (int jc = 0; jc < 4; ++jc) a[jc] = as_[k * DIM + tc + 32 * jc];
        #pragma unroll
        for (int ir = 0; ir < 2; ++ir) {
            float zv = zts[tr * 2 + ir][k];
            #pragma unroll
            for (int jc = 0; jc < 4; ++jc) s[ir][jc] = fmaf(zv, a[jc], s[ir][jc]);
        }
    }
    __syncthreads();   // done reading z; buffer will be overwritten with t

    // ---- phase 3: t[b,i] = sum_c tanh(s*v[c]+bg1[c]) * Wg2[c] ----
    #pragma unroll
    for (int ir = 0; ir < 2; ++ir) {
        #pragma unroll
        for (int jc = 0; jc < 4; ++jc) {
            const float sv = s[ir][jc];
            float tv = 0.0f;
            for (int c = 0; c < DC2; ++c) {
                float arg = fmaf(sv, vc[c], bgs[c]);
                float e = __expf(2.0f * arg);
                float th = 1.0f - 2.0f * __builtin_amdgcn_rcpf(e + 1.0f);
                tv = fmaf(w2s[c], th, tv);
            }
            zts[tr * 2 + ir][tc + 32 * jc] = tv;
        }
    }
    __syncthreads();

    // ---- phase 4: x_hat = t @ ahat + bg2 ----
    const float bg2v = bg2[0];
    float xh[2][4] = {};
    for (int k = 0; k < DIM; ++k) {
        float a[4];
        #pragma unroll
        for (int jc = 0; jc < 4; ++jc) a[jc] = as_[k * DIM + tc + 32 * jc];
        #pragma unroll
        for (int ir = 0; ir < 2; ++ir) {
            float tv = zts[tr * 2 + ir][k];
            #pragma unroll
            for (int jc = 0; jc < 4; ++jc) xh[ir][jc] = fmaf(tv, a[jc], xh[ir][jc]);
        }
    }
    #pragma unroll
    for (int ir = 0; ir < 2; ++ir)
        #pragma unroll
        for (int jc = 0; jc < 4; ++jc)
            out[OUT_XHAT + (size_t)(row0 + tr * 2 + ir) * DIM + tc + 32 * jc] =
                xh[ir][jc] + bg2v;
}

// ---------------------------------------------------------------------------
extern "C" void kernel_launch(void* const* d_in, const int* in_sizes, int n_in,
                              void* d_out, int out_size, void* d_ws, size_t ws_size,
                              hipStream_t stream)
{
    const float* x      = (const float*)d_in[0];
    const float* eps    = (const float*)d_in[1];
    const float* W1     = (const float*)d_in[2];
    const float* b1     = (const float*)d_in[3];
    const float* W2     = (const float*)d_in[4];
    const float* b2     = (const float*)d_in[5];
    const float* Wmu    = (const float*)d_in[6];
    const float* bmu    = (const float*)d_in[7];
    const float* Wlv    = (const float*)d_in[8];
    const float* blv    = (const float*)d_in[9];
    const float* logits = (const float*)d_in[10];
    const float* Wf     = (const float*)d_in[11];
    const float* Wg1    = (const float*)d_in[12];
    const float* bg1    = (const float*)d_in[13];
    const float* Wg2    = (const float*)d_in[14];
    const float* bg2    = (const float*)d_in[15];
    const int*   itp    = (const int*)d_in[16];
    float* out = (float*)d_out;
    float* ws  = (float*)d_ws;

    hipLaunchKernelGGL(graph_kernel, dim3(1), dim3(128), 0, stream,
                       logits, Wf, Wg1, itp, out, ws);
    hipLaunchKernelGGL(encoder_kernel, dim3(BATCH / BR), dim3(256), 0, stream,
                       x, eps, W1, b1, W2, b2, Wmu, bmu, Wlv, blv, out, ws);
    hipLaunchKernelGGL(decoder_kernel, dim3(BATCH / BRC), dim3(256), 0, stream,
                       bg1, Wg2, bg2, out, ws);
}

// Round 2
// 84.408 us; speedup vs baseline: 1.1386x; 1.1386x over previous
//
#include <hip/hip_runtime.h>
#include <math.h>

#define BATCH 8192
#define DIM   128
#define E1    256
#define E2    128
#define DC1   64
#define DC2   32

// output float offsets (x_hat, adj, mu, lv concatenated)
#define OUT_XHAT 0
#define OUT_ADJ  (BATCH*DIM)                 // 1048576
#define OUT_MU   (OUT_ADJ + DIM*DIM)         // 1064960
#define OUT_LV   (OUT_MU + BATCH*DIM)        // 2113536

// workspace float offsets
#define WS_AHAT 0
#define WS_V    (DIM*DIM)                    // 16384
#define WS_Z    (WS_V + 64)                  // 16448

#define BR  16   // encoder batch rows per block
#define BRC 16   // decoder batch rows per block

// ---------------------------------------------------------------------------
// Kernel 1: block 0 = graph (adj, a_hat, v); blocks 1..512 = fused VAE encoder.
// 512 threads/block, LDS 67 KB -> 2 blocks/CU -> 4 waves/SIMD.
// ---------------------------------------------------------------------------
__global__ __launch_bounds__(512, 4) void enc_graph_kernel(
    const float* __restrict__ x,   const float* __restrict__ eps,
    const float* __restrict__ W1,  const float* __restrict__ b1,
    const float* __restrict__ W2,  const float* __restrict__ b2,
    const float* __restrict__ Wmu, const float* __restrict__ bmu,
    const float* __restrict__ Wlv, const float* __restrict__ blv,
    const float* __restrict__ logits, const float* __restrict__ Wf,
    const float* __restrict__ Wg1, const int* __restrict__ itp,
    float* __restrict__ out, float* __restrict__ ws)
{
    __shared__ float smem[16384];   // 64 KB, unioned between graph / encoder
    __shared__ float aux[768];
    const int t = threadIdx.x;

    if (blockIdx.x == 0) {
        // ----------------- graph block -----------------
        const int it = itp[0];
        {
            const int j = t & 127, rq = t >> 7;      // column j, row-quarter
            float dp = 0.0f;
            for (int i = rq * 32; i < rq * 32 + 32; ++i) {
                float l = logits[i * DIM + j];
                float gv = 1.0f / (1.0f + expf(-l)); // precise expf: threshold boundary
                if (i == j) gv = 1.0f;
                if (it > 50 && gv < 0.1f) gv = 0.0f;
                smem[i * DIM + j] = gv;
                if (gv > 0.0f) dp += 1.0f;
            }
            aux[rq * 128 + j] = dp;                  // partial col-sums (d_in)
        }
        __syncthreads();
        if (t < 128) {
            float d = aux[t] + aux[128 + t] + aux[256 + t] + aux[384 + t];
            aux[512 + t] = 1.0f / sqrtf(fmaxf(d, 1.0f));   // rin[j]  (d_in)
        }
        __syncthreads();
        {
            const int i = t & 127, cq = t >> 7;      // row i, col-quarter
            float dp = 0.0f;
            for (int c = cq * 32; c < cq * 32 + 32; ++c)
                if (smem[i * DIM + c] > 0.0f) dp += 1.0f;
            aux[cq * 128 + i] = dp;                  // partial row-sums (d_out)
        }
        __syncthreads();
        if (t < 128) {
            float d = aux[t] + aux[128 + t] + aux[256 + t] + aux[384 + t];
            aux[640 + t] = 1.0f / sqrtf(fmaxf(d, 1.0f));   // rdout[i] (d_out)
        }
        __syncthreads();
        for (int p = 0; p < 32; ++p) {
            int idx = t + 512 * p;
            int i = idx >> 7, j = idx & 127;
            float gv = smem[idx];
            out[OUT_ADJ + idx] = gv;
            ws[WS_AHAT + idx] = gv * aux[640 + i] * aux[512 + j];
        }
        if (t < DC2) {      // v = W_feat (1x64) @ W_g1 (64x32)
            float acc = 0.0f;
            for (int k = 0; k < DC1; ++k) acc += Wf[k] * Wg1[k * DC2 + t];
            ws[WS_V + t] = acc;
        }
        return;
    }

    // ----------------- encoder block -----------------
    float* xs    = smem;            // [16][128]   2048 floats
    float* wtile = smem + 2048;     // 8192 floats (32 KB weight chunk)
    float* h1s   = smem + 10240;    // [16][256]   4096 floats
    float* h2s   = smem + 14336;    // [16][128]   2048 floats
    const int row0 = (int)(blockIdx.x - 1) * BR;

    // stage x tile (2048 floats, 1 float4/thread)
    ((float4*)xs)[t] = ((const float4*)(x + (size_t)row0 * DIM))[t];

    // ---- layer 1: h1 = relu(x@W1+b1), 16x256; thread = 2 rows x 4 consec cols
    const int tc1 = t & 63, tr1 = t >> 6;    // tr1 wave-uniform -> LDS broadcast
    float acc1[2][4] = {};
    for (int kc = 0; kc < 4; ++kc) {         // k-chunks of 32 rows (32 KB)
        __syncthreads();                     // xs ready / wtile consumed
        {
            const float4* wg = (const float4*)(W1 + kc * 32 * E1);
            float4* wl = (float4*)wtile;
            #pragma unroll
            for (int p = 0; p < 4; ++p) wl[t + 512 * p] = wg[t + 512 * p];
        }
        __syncthreads();
        #pragma unroll
        for (int kk = 0; kk < 32; kk += 4) {
            float4 xv0 = *(const float4*)&xs[(tr1 * 2 + 0) * DIM + kc * 32 + kk];
            float4 xv1 = *(const float4*)&xs[(tr1 * 2 + 1) * DIM + kc * 32 + kk];
            const float* x0 = (const float*)&xv0;
            const float* x1 = (const float*)&xv1;
            #pragma unroll
            for (int q = 0; q < 4; ++q) {
                float4 w = *(const float4*)&wtile[(kk + q) * E1 + tc1 * 4];
                const float* wp = (const float*)&w;
                #pragma unroll
                for (int c = 0; c < 4; ++c) {
                    acc1[0][c] = fmaf(x0[q], wp[c], acc1[0][c]);
                    acc1[1][c] = fmaf(x1[q], wp[c], acc1[1][c]);
                }
            }
        }
    }
    __syncthreads();
    {
        float4 bb4 = *(const float4*)&b1[tc1 * 4];
        const float* bb = (const float*)&bb4;
        #pragma unroll
        for (int c = 0; c < 4; ++c) {
            h1s[(tr1 * 2 + 0) * E1 + tc1 * 4 + c] = fmaxf(acc1[0][c] + bb[c], 0.0f);
            h1s[(tr1 * 2 + 1) * E1 + tc1 * 4 + c] = fmaxf(acc1[1][c] + bb[c], 0.0f);
        }
    }

    // ---- layer 2: h2 = relu(h1@W2+b2), 16x128; thread = 1 row x 4 cols
    const int tc2 = t & 31, tr2 = t >> 5;    // tr2 half-wave-uniform
    float acc2[4] = {};
    for (int kc = 0; kc < 4; ++kc) {         // k-chunks of 64 rows (32 KB)
        __syncthreads();                     // h1s ready / wtile consumed
        {
            const float4* wg = (const float4*)(W2 + kc * 64 * E2);
            float4* wl = (float4*)wtile;
            #pragma unroll
            for (int p = 0; p < 4; ++p) wl[t + 512 * p] = wg[t + 512 * p];
        }
        __syncthreads();
        #pragma unroll
        for (int kk = 0; kk < 64; kk += 4) {
            float4 hv = *(const float4*)&h1s[tr2 * E1 + kc * 64 + kk];
            const float* hp = (const float*)&hv;
            #pragma unroll
            for (int q = 0; q < 4; ++q) {
                float4 w = *(const float4*)&wtile[(kk + q) * E2 + tc2 * 4];
                const float* wp = (const float*)&w;
                #pragma unroll
                for (int c = 0; c < 4; ++c) acc2[c] = fmaf(hp[q], wp[c], acc2[c]);
            }
        }
    }
    __syncthreads();
    {
        float4 bb4 = *(const float4*)&b2[tc2 * 4];
        const float* bb = (const float*)&bb4;
        #pragma unroll
        for (int c = 0; c < 4; ++c)
            h2s[tr2 * DIM + tc2 * 4 + c] = fmaxf(acc2[c] + bb[c], 0.0f);
    }

    // ---- mu & lv (Wmu/Wlv chunks staged together), thread = 1 row x 4 cols
    float amu[4] = {}, alv[4] = {};
    for (int kc = 0; kc < 4; ++kc) {         // k-chunks of 32 rows each (2x16 KB)
        __syncthreads();
        {
            const float4* wgm = (const float4*)(Wmu + kc * 32 * DIM);
            const float4* wgl = (const float4*)(Wlv + kc * 32 * DIM);
            float4* wl = (float4*)wtile;
            #pragma unroll
            for (int p = 0; p < 2; ++p) wl[t + 512 * p] = wgm[t + 512 * p];
            #pragma unroll
            for (int p = 0; p < 2; ++p) wl[1024 + t + 512 * p] = wgl[t + 512 * p];
        }
        __syncthreads();
        #pragma unroll
        for (int kk = 0; kk < 32; kk += 4) {
            float4 hv = *(const float4*)&h2s[tr2 * DIM + kc * 32 + kk];
            const float* hp = (const float*)&hv;
            #pragma unroll
            for (int q = 0; q < 4; ++q) {
                float4 wm = *(const float4*)&wtile[(kk + q) * DIM + tc2 * 4];
                float4 wv = *(const float4*)&wtile[4096 + (kk + q) * DIM + tc2 * 4];
                const float* wmp = (const float*)&wm;
                const float* wvp = (const float*)&wv;
                #pragma unroll
                for (int c = 0; c < 4; ++c) {
                    amu[c] = fmaf(hp[q], wmp[c], amu[c]);
                    alv[c] = fmaf(hp[q], wvp[c], alv[c]);
                }
            }
        }
    }

    // ---- epilogue: mu, lv, z = mu + eps*exp(0.5*lv)
    {
        const int gbase = (row0 + tr2) * DIM + tc2 * 4;
        float4 bm4 = *(const float4*)&bmu[tc2 * 4];
        float4 bl4 = *(const float4*)&blv[tc2 * 4];
        float4 ev4 = *(const float4*)&eps[gbase];
        const float* bm = (const float*)&bm4;
        const float* bl = (const float*)&bl4;
        const float* ev = (const float*)&ev4;
        float mu4[4], lv4[4], z4[4];
        #pragma unroll
        for (int c = 0; c < 4; ++c) {
            float mu = amu[c] + bm[c];
            float lv = alv[c] + bl[c];
            mu4[c] = mu;
            lv4[c] = lv;
            z4[c] = fmaf(ev[c], __expf(0.5f * lv), mu);
        }
        *(float4*)&out[OUT_MU + gbase] = *(float4*)mu4;
        *(float4*)&out[OUT_LV + gbase] = *(float4*)lv4;
        *(float4*)&ws[WS_Z + gbase]   = *(float4*)z4;
    }
}

// ---------------------------------------------------------------------------
// Kernel 2: fused GCN decoder. a_hat streamed from L1/L2 (no 64 KB LDS copy).
// s = z@ahat ; t = sum_c tanh(s*v+b)*w2 ; xhat = t@ahat + bg2
// 512 threads, 16 rows/block, thread = 1 row x 4 consec cols.
// ---------------------------------------------------------------------------
__global__ __launch_bounds__(512, 4) void decoder_kernel(
    const float* __restrict__ bg1, const float* __restrict__ Wg2,
    const float* __restrict__ bg2,
    float* __restrict__ out, const float* __restrict__ ws)
{
    __shared__ float zts[BRC * DIM];     // 8 KB: z in phase 2, t in phase 3/4
    __shared__ float vc[DC2], bgs[DC2], w2s[DC2];
    const int t = threadIdx.x;
    const int row0 = blockIdx.x * BRC;
    const float* ahat = ws + WS_AHAT;

    ((float4*)zts)[t] = ((const float4*)(ws + WS_Z + (size_t)row0 * DIM))[t];
    if (t < DC2) { vc[t] = ws[WS_V + t]; bgs[t] = bg1[t]; w2s[t] = Wg2[t]; }
    __syncthreads();

    const int tc = t & 31, tr = t >> 5;
    const int col = tc * 4;

    // ---- phase 2: s = z @ ahat
    float s[4] = {};
    #pragma unroll 2
    for (int k = 0; k < DIM; k += 4) {
        float4 zv = *(const float4*)&zts[tr * DIM + k];
        const float* zp = (const float*)&zv;
        #pragma unroll
        for (int q = 0; q < 4; ++q) {
            float4 a = *(const float4*)&ahat[(k + q) * DIM + col];
            const float* ap = (const float*)&a;
            #pragma unroll
            for (int c = 0; c < 4; ++c) s[c] = fmaf(zp[q], ap[c], s[c]);
        }
    }
    __syncthreads();      // done reading z

    // ---- phase 3: t = sum_c tanh(s*v[c]+bg1[c]) * Wg2[c]
    float tv[4] = {};
    #pragma unroll 4
    for (int c = 0; c < DC2; ++c) {
        float vcc = vc[c], bgc = bgs[c], w2c = w2s[c];
        #pragma unroll
        for (int o = 0; o < 4; ++o) {
            float arg = fmaf(s[o], vcc, bgc);
            float e = __expf(2.0f * arg);
            float th = 1.0f - 2.0f * __builtin_amdgcn_rcpf(e + 1.0f);
            tv[o] = fmaf(w2c, th, tv[o]);
        }
    }
    *(float4*)&zts[tr * DIM + col] = *(float4*)tv;
    __syncthreads();

    // ---- phase 4: x_hat = t @ ahat + bg2
    float xh[4] = {};
    #pragma unroll 2
    for (int k = 0; k < DIM; k += 4) {
        float4 tvv = *(const float4*)&zts[tr * DIM + k];
        const float* tp = (const float*)&tvv;
        #pragma unroll
        for (int q = 0; q < 4; ++q) {
            float4 a = *(const float4*)&ahat[(k + q) * DIM + col];
            const float* ap = (const float*)&a;
            #pragma unroll
            for (int c = 0; c < 4; ++c) xh[c] = fmaf(tp[q], ap[c], xh[c]);
        }
    }
    const float bg2v = bg2[0];
    float o4[4];
    #pragma unroll
    for (int c = 0; c < 4; ++c) o4[c] = xh[c] + bg2v;
    *(float4*)&out[OUT_XHAT + (size_t)(row0 + tr) * DIM + col] = *(float4*)o4;
}

// ---------------------------------------------------------------------------
extern "C" void kernel_launch(void* const* d_in, const int* in_sizes, int n_in,
                              void* d_out, int out_size, void* d_ws, size_t ws_size,
                              hipStream_t stream)
{
    const float* x      = (const float*)d_in[0];
    const float* eps    = (const float*)d_in[1];
    const float* W1     = (const float*)d_in[2];
    const float* b1     = (const float*)d_in[3];
    const float* W2     = (const float*)d_in[4];
    const float* b2     = (const float*)d_in[5];
    const float* Wmu    = (const float*)d_in[6];
    const float* bmu    = (const float*)d_in[7];
    const float* Wlv    = (const float*)d_in[8];
    const float* blv    = (const float*)d_in[9];
    const float* logits = (const float*)d_in[10];
    const float* Wf     = (const float*)d_in[11];
    const float* Wg1    = (const float*)d_in[12];
    const float* bg1    = (const float*)d_in[13];
    const float* Wg2    = (const float*)d_in[14];
    const float* bg2    = (const float*)d_in[15];
    const int*   itp    = (const int*)d_in[16];
    float* out = (float*)d_out;
    float* ws  = (float*)d_ws;

    hipLaunchKernelGGL(enc_graph_kernel, dim3(BATCH / BR + 1), dim3(512), 0, stream,
                       x, eps, W1, b1, W2, b2, Wmu, bmu, Wlv, blv,
                       logits, Wf, Wg1, itp, out, ws);
    hipLaunchKernelGGL(decoder_kernel, dim3(BATCH / BRC), dim3(512), 0, stream,
                       bg1, Wg2, bg2, out, ws);
}

// Round 3
// 26.278 us; speedup vs baseline: 3.6572x; 3.2122x over previous
//
#include <hip/hip_runtime.h>
#include <math.h>

#define BATCH 8192
#define DIM   128
#define E1    256
#define E2    128

// output float offsets (x_hat, adj, mu, lv concatenated)
#define OUT_XHAT 0
#define OUT_ADJ  (BATCH*DIM)                 // 1048576
#define OUT_MU   (OUT_ADJ + DIM*DIM)         // 1064960
#define OUT_LV   (OUT_MU + BATCH*DIM)        // 2113536

// workspace BYTE offsets (frag-linear bf16 weight images + small f32 blocks)
#define W1F   0u          // 32768 bf16 = 65536 B
#define W2F   65536u      // 32768 bf16
#define WMUF  131072u     // 16384 bf16 = 32768 B
#define WLVF  163840u     // 16384 bf16
#define AHF   196608u     // 16384 bf16
#define COEF  229376u     // f32[8]: a1,a3,a5,s_safe
#define VBUF  229408u     // f32[96]: v[32], bg1[32], w2[32]

typedef __attribute__((ext_vector_type(8))) short s8v;   // 8 bf16 (4 VGPR)
typedef __attribute__((ext_vector_type(4))) float f4v;   // MFMA accumulator
#define MFMA(a, b, c) __builtin_amdgcn_mfma_f32_16x16x32_bf16(a, b, c, 0, 0, 0)

__device__ __forceinline__ ushort f2bf(float f) {        // RNE f32 -> bf16
    uint u = __float_as_uint(f);
    u += 0x7fffu + ((u >> 16) & 1u);
    return (ushort)(u >> 16);
}

// ---------------------------------------------------------------------------
// Kernel 1 (prep): blocks 0-23 convert weights f32 -> fragment-linear bf16.
// Block 24: adjacency, a_hat frags, tanh-poly coefficients.
// Fragment-linear layout for a K x N matrix: frag (nt, ks) holds the 16x32
// tile cols [nt*16,+16) x rows [ks*32,+32); elem ((nt*nKs+ks)*64 + l)*8 + j
// stores W[ks*32 + (l>>4)*8 + j][nt*16 + (l&15)].
// ---------------------------------------------------------------------------
__global__ __launch_bounds__(512) void prep_kernel(
    const float* __restrict__ W1,  const float* __restrict__ W2,
    const float* __restrict__ Wmu, const float* __restrict__ Wlv,
    const float* __restrict__ logits, const float* __restrict__ Wf,
    const float* __restrict__ Wg1, const float* __restrict__ bg1,
    const float* __restrict__ Wg2, const int* __restrict__ itp,
    float* __restrict__ out, char* __restrict__ wsb)
{
    __shared__ float gsm[16384];
    __shared__ float aux[768];
    __shared__ float vsh[32];
    const int t = threadIdx.x;

    if (blockIdx.x < 24) {
        // ---------------- weight fragment conversion ----------------
        const int tid = (int)blockIdx.x * 512 + t;       // 0..12287
        const float* W; ushort* dst; int e, N_, ksLog;
        if (tid < 4096)       { W = W1;  dst = (ushort*)(wsb + W1F);  e = tid * 8;           N_ = 256; ksLog = 2; }
        else if (tid < 8192)  { W = W2;  dst = (ushort*)(wsb + W2F);  e = (tid - 4096) * 8;  N_ = 128; ksLog = 3; }
        else if (tid < 10240) { W = Wmu; dst = (ushort*)(wsb + WMUF); e = (tid - 8192) * 8;  N_ = 128; ksLog = 2; }
        else                  { W = Wlv; dst = (ushort*)(wsb + WLVF); e = (tid - 10240) * 8; N_ = 128; ksLog = 2; }
        const int frag = e >> 9, l = (e >> 3) & 63;
        const int nt = frag >> ksLog, ks = frag & ((1 << ksLog) - 1);
        const int k0 = ks * 32 + ((l >> 4) << 3);
        const int n  = (nt << 4) + (l & 15);
        uint pk[4];
        #pragma unroll
        for (int jj = 0; jj < 4; ++jj) {
            ushort lo = f2bf(W[(k0 + 2 * jj) * N_ + n]);
            ushort hi = f2bf(W[(k0 + 2 * jj + 1) * N_ + n]);
            pk[jj] = (uint)lo | ((uint)hi << 16);
        }
        *(uint4*)(dst + e) = make_uint4(pk[0], pk[1], pk[2], pk[3]);
        return;
    }

    // ---------------- graph block ----------------
    const int it = itp[0];
    {
        const int j = t & 127, rq = t >> 7;
        float dp = 0.0f;
        for (int i = rq * 32; i < rq * 32 + 32; ++i) {
            float l = logits[i * DIM + j];
            float gv = 1.0f / (1.0f + expf(-l));   // precise: threshold boundary
            if (i == j) gv = 1.0f;
            if (it > 50 && gv < 0.1f) gv = 0.0f;
            gsm[i * DIM + j] = gv;
            if (gv > 0.0f) dp += 1.0f;
        }
        aux[rq * 128 + j] = dp;                    // partial col sums (d_in)
    }
    __syncthreads();
    if (t < 128) {
        float d = aux[t] + aux[128 + t] + aux[256 + t] + aux[384 + t];
        aux[512 + t] = 1.0f / sqrtf(fmaxf(d, 1.0f));      // rin[j]
    }
    __syncthreads();
    {
        const int i = t & 127, cq = t >> 7;
        float dp = 0.0f;
        for (int c = cq * 32; c < cq * 32 + 32; ++c)
            if (gsm[i * DIM + c] > 0.0f) dp += 1.0f;
        aux[cq * 128 + i] = dp;                    // partial row sums (d_out)
    }
    __syncthreads();
    if (t < 128) {
        float d = aux[t] + aux[128 + t] + aux[256 + t] + aux[384 + t];
        aux[640 + t] = 1.0f / sqrtf(fmaxf(d, 1.0f));      // rdout[i]
    }
    __syncthreads();
    for (int p = 0; p < 32; ++p) {                 // adj out + ahat in place
        int idx = t + 512 * p;
        int i = idx >> 7, j = idx & 127;
        float gv = gsm[idx];
        out[OUT_ADJ + idx] = gv;
        gsm[idx] = gv * aux[640 + i] * aux[512 + j];
    }
    if (t < 32) {                                  // v = W_feat @ W_g1
        float acc = 0.0f;
        for (int k = 0; k < 64; ++k) acc = fmaf(Wf[k], Wg1[k * 32 + t], acc);
        vsh[t] = acc;
        float* vb = (float*)(wsb + VBUF);
        vb[t] = acc; vb[32 + t] = bg1[t]; vb[64 + t] = Wg2[t];
    }
    __syncthreads();
    {                                              // ahat fragments (K=N=128)
        ushort* ahf = (ushort*)(wsb + AHF);
        #pragma unroll
        for (int c = 0; c < 4; ++c) {
            int e = (t + c * 512) * 8;
            int frag = e >> 9, l = (e >> 3) & 63;
            int nt = frag >> 2, ks = frag & 3;
            int k0 = ks * 32 + ((l >> 4) << 3);
            int n  = (nt << 4) + (l & 15);
            uint pk[4];
            #pragma unroll
            for (int jj = 0; jj < 4; ++jj) {
                ushort lo = f2bf(gsm[(k0 + 2 * jj) * DIM + n]);
                ushort hi = f2bf(gsm[(k0 + 2 * jj + 1) * DIM + n]);
                pk[jj] = (uint)lo | ((uint)hi << 16);
            }
            *(uint4*)(ahf + e) = make_uint4(pk[0], pk[1], pk[2], pk[3]);
        }
    }
    if (t == 0) {                                  // tanh poly coefficients
        float a1 = 0, a3 = 0, a5 = 0, vmax = 0, bmax = 0;
        for (int c = 0; c < 32; ++c) {
            float v = vsh[c], w = Wg2[c], v2 = v * v;
            a1 += w * v;
            a3 -= w * v * v2 * (1.0f / 3.0f);
            a5 += w * v * v2 * v2 * (2.0f / 15.0f);
            vmax = fmaxf(vmax, fabsf(v));
            bmax = fmaxf(bmax, fabsf(bg1[c]));
        }
        float* cf = (float*)(wsb + COEF);
        cf[0] = a1; cf[1] = a3; cf[2] = a5;
        cf[3] = (bmax == 0.0f) ? 0.2f / fmaxf(vmax, 1e-30f) : -1.0f;
    }
}

// ---------------------------------------------------------------------------
// Kernel 2 (fused): per block = 16 batch rows, full encoder + GCN decoder.
// All GEMMs via v_mfma_f32_16x16x32_bf16. 256 threads = 4 waves; wave w owns
// output-column slice. z stays on-chip (reg -> LDS frag restage).
// ---------------------------------------------------------------------------
__global__ __launch_bounds__(256, 2) void fused_kernel(
    const float* __restrict__ x,   const float* __restrict__ eps,
    const float* __restrict__ b1,  const float* __restrict__ b2,
    const float* __restrict__ bmu, const float* __restrict__ blv,
    const float* __restrict__ bg2p,
    float* __restrict__ out, char* __restrict__ wsb)
{
    __shared__ __attribute__((aligned(16))) ushort bufA[2048]; // x frags, then z frags
    __shared__ __attribute__((aligned(16))) ushort bufB[4096]; // h1 frags, then t frags
    __shared__ __attribute__((aligned(16))) ushort bufC[2048]; // h2 frags
    __shared__ float vls[96];

    const int t = threadIdx.x;
    const int lane = t & 63, wid = t >> 6;
    const int fr = lane & 15, fq = lane >> 4;       // C/D: col=fr, rows=fq*4+q
    const int row0 = (int)blockIdx.x * 16;

    if (t < 96) vls[t] = ((const float*)(wsb + VBUF))[t];

    // ---- stage x tile -> bf16 fragments (thread -> one (r,g,ks) 8-chunk) ----
    {
        const int r = t & 15, g = (t >> 4) & 3, ks = t >> 6;
        const float* src = x + (size_t)(row0 + r) * DIM + ks * 32 + g * 8;
        float4 u0 = *(const float4*)src;
        float4 u1 = *(const float4*)(src + 4);
        uint p0 = (uint)f2bf(u0.x) | ((uint)f2bf(u0.y) << 16);
        uint p1 = (uint)f2bf(u0.z) | ((uint)f2bf(u0.w) << 16);
        uint p2 = (uint)f2bf(u1.x) | ((uint)f2bf(u1.y) << 16);
        uint p3 = (uint)f2bf(u1.z) | ((uint)f2bf(u1.w) << 16);
        *(uint4*)&bufA[(ks * 64 + g * 16 + r) * 8] = make_uint4(p0, p1, p2, p3);
    }
    __syncthreads();

    // ---- layer 1: h1 = relu(x@W1+b1), N=256, wave w -> cols [w*64, +64) ----
    {
        const ushort* w1f = (const ushort*)(wsb + W1F);
        f4v acc[4] = {{0,0,0,0},{0,0,0,0},{0,0,0,0},{0,0,0,0}};
        #pragma unroll
        for (int ks = 0; ks < 4; ++ks) {
            s8v a = *(const s8v*)&bufA[(ks * 64 + lane) * 8];
            #pragma unroll
            for (int n = 0; n < 4; ++n) {
                s8v b = *(const s8v*)&w1f[(((wid * 4 + n) * 4 + ks) * 64 + lane) * 8];
                acc[n] = MFMA(a, b, acc[n]);
            }
        }
        __syncthreads();            // all xf reads done (bufA reused later for z)
        #pragma unroll
        for (int n = 0; n < 4; ++n) {
            int col = wid * 64 + n * 16 + fr;       // k2 for layer 2
            float bb = b1[col];
            int base = (col >> 5) * 512 + (((col >> 3) & 3) * 16) * 8 + (col & 7);
            #pragma unroll
            for (int q = 0; q < 4; ++q)
                bufB[base + (fq * 4 + q) * 8] = f2bf(fmaxf(acc[n][q] + bb, 0.0f));
        }
    }
    __syncthreads();

    // ---- layer 2: h2 = relu(h1@W2+b2), K=256, N=128, wave -> cols [w*32,+32) ----
    {
        const ushort* w2f = (const ushort*)(wsb + W2F);
        f4v acc[2] = {{0,0,0,0},{0,0,0,0}};
        #pragma unroll
        for (int ks = 0; ks < 8; ++ks) {
            s8v a = *(const s8v*)&bufB[(ks * 64 + lane) * 8];
            #pragma unroll
            for (int n = 0; n < 2; ++n) {
                s8v b = *(const s8v*)&w2f[(((wid * 2 + n) * 8 + ks) * 64 + lane) * 8];
                acc[n] = MFMA(a, b, acc[n]);
            }
        }
        #pragma unroll
        for (int n = 0; n < 2; ++n) {
            int col = wid * 32 + n * 16 + fr;
            float bb = b2[col];
            int base = (col >> 5) * 512 + (((col >> 3) & 3) * 16) * 8 + (col & 7);
            #pragma unroll
            for (int q = 0; q < 4; ++q)
                bufC[base + (fq * 4 + q) * 8] = f2bf(fmaxf(acc[n][q] + bb, 0.0f));
        }
    }
    __syncthreads();

    // ---- mu / lv + z (fused) ----
    {
        const ushort* wmf = (const ushort*)(wsb + WMUF);
        const ushort* wlf = (const ushort*)(wsb + WLVF);
        f4v am[2] = {{0,0,0,0},{0,0,0,0}}, al[2] = {{0,0,0,0},{0,0,0,0}};
        #pragma unroll
        for (int ks = 0; ks < 4; ++ks) {
            s8v a = *(const s8v*)&bufC[(ks * 64 + lane) * 8];
            #pragma unroll
            for (int n = 0; n < 2; ++n) {
                int fi = (((wid * 2 + n) * 4 + ks) * 64 + lane) * 8;
                s8v bm = *(const s8v*)&wmf[fi];
                s8v bl = *(const s8v*)&wlf[fi];
                am[n] = MFMA(a, bm, am[n]);
                al[n] = MFMA(a, bl, al[n]);
            }
        }
        #pragma unroll
        for (int n = 0; n < 2; ++n) {
            int col = wid * 32 + n * 16 + fr;
            float bm = bmu[col], bl = blv[col];
            int base = (col >> 5) * 512 + (((col >> 3) & 3) * 16) * 8 + (col & 7);
            #pragma unroll
            for (int q = 0; q < 4; ++q) {
                int grow = row0 + fq * 4 + q;
                float mu = am[n][q] + bm;
                float lv = al[n][q] + bl;
                out[OUT_MU + grow * DIM + col] = mu;
                out[OUT_LV + grow * DIM + col] = lv;
                float z = fmaf(eps[grow * DIM + col], __expf(0.5f * lv), mu);
                bufA[base + (fq * 4 + q) * 8] = f2bf(z);   // z frags into bufA
            }
        }
    }
    __syncthreads();

    // ---- decoder: s = z@ahat ; t = P(s) ; xhat = t@ahat + bg2 ----
    const ushort* ahf = (const ushort*)(wsb + AHF);
    const float* cf = (const float*)(wsb + COEF);
    const float a1 = cf[0], a3 = cf[1], a5 = cf[2], ssafe = cf[3];

    s8v bfr[2][4];
    #pragma unroll
    for (int n = 0; n < 2; ++n)
        #pragma unroll
        for (int ks = 0; ks < 4; ++ks)
            bfr[n][ks] = *(const s8v*)&ahf[(((wid * 2 + n) * 4 + ks) * 64 + lane) * 8];

    f4v sa[2] = {{0,0,0,0},{0,0,0,0}};
    #pragma unroll
    for (int ks = 0; ks < 4; ++ks) {
        s8v a = *(const s8v*)&bufA[(ks * 64 + lane) * 8];
        sa[0] = MFMA(a, bfr[0][ks], sa[0]);
        sa[1] = MFMA(a, bfr[1][ks], sa[1]);
    }
    __syncthreads();                 // bufB free (layer-2 reads long done)

    #pragma unroll
    for (int n = 0; n < 2; ++n) {
        int k2 = wid * 32 + n * 16 + fr;
        int base = (k2 >> 5) * 512 + (((k2 >> 3) & 3) * 16) * 8 + (k2 & 7);
        #pragma unroll
        for (int q = 0; q < 4; ++q) {
            float s = sa[n][q];
            float tv;
            if (fabsf(s) < ssafe) {                 // poly path (always, in practice)
                float s2 = s * s;
                tv = s * fmaf(s2, fmaf(s2, a5, a3), a1);
            } else {                                // exact fallback
                tv = 0.0f;
                for (int c = 0; c < 32; ++c)
                    tv = fmaf(vls[64 + c], tanhf(fmaf(s, vls[c], vls[32 + c])), tv);
            }
            bufB[base + (fq * 4 + q) * 8] = f2bf(tv);
        }
    }
    __syncthreads();

    f4v xa[2] = {{0,0,0,0},{0,0,0,0}};
    #pragma unroll
    for (int ks = 0; ks < 4; ++ks) {
        s8v a = *(const s8v*)&bufB[(ks * 64 + lane) * 8];
        xa[0] = MFMA(a, bfr[0][ks], xa[0]);
        xa[1] = MFMA(a, bfr[1][ks], xa[1]);
    }
    const float bg2v = bg2p[0];
    #pragma unroll
    for (int n = 0; n < 2; ++n) {
        int col = wid * 32 + n * 16 + fr;
        #pragma unroll
        for (int q = 0; q < 4; ++q)
            out[OUT_XHAT + (size_t)(row0 + fq * 4 + q) * DIM + col] = xa[n][q] + bg2v;
    }
}

// ---------------------------------------------------------------------------
extern "C" void kernel_launch(void* const* d_in, const int* in_sizes, int n_in,
                              void* d_out, int out_size, void* d_ws, size_t ws_size,
                              hipStream_t stream)
{
    const float* x      = (const float*)d_in[0];
    const float* eps    = (const float*)d_in[1];
    const float* W1     = (const float*)d_in[2];
    const float* b1     = (const float*)d_in[3];
    const float* W2     = (const float*)d_in[4];
    const float* b2     = (const float*)d_in[5];
    const float* Wmu    = (const float*)d_in[6];
    const float* bmu    = (const float*)d_in[7];
    const float* Wlv    = (const float*)d_in[8];
    const float* blv    = (const float*)d_in[9];
    const float* logits = (const float*)d_in[10];
    const float* Wf     = (const float*)d_in[11];
    const float* Wg1    = (const float*)d_in[12];
    const float* bg1    = (const float*)d_in[13];
    const float* Wg2    = (const float*)d_in[14];
    const float* bg2    = (const float*)d_in[15];
    const int*   itp    = (const int*)d_in[16];
    float* out = (float*)d_out;
    char* wsb  = (char*)d_ws;

    hipLaunchKernelGGL(prep_kernel, dim3(25), dim3(512), 0, stream,
                       W1, W2, Wmu, Wlv, logits, Wf, Wg1, bg1, Wg2, itp, out, wsb);
    hipLaunchKernelGGL(fused_kernel, dim3(BATCH / 16), dim3(256), 0, stream,
                       x, eps, b1, b2, bmu, blv, bg2, out, wsb);
}